// Round 7
// baseline (185.054 us; speedup 1.0000x reference)
//
#include <hip/hip_runtime.h>
#include <stdint.h>

// Problem constants (fixed by the reference setup):
//   logits (2,4,128,128,128) fp32, target one-hot same shape.
#define NVOX (1u << 21)            // 128^3 voxels per batch (exactly 2^21)
#define NB   2                     // batches
#define KSEL 419430u               // int(0.2 * 2^21)
#define TPB  256
#define VPB  2048                  // voxels per block -> 2048 blocks = 8/CU resident
#define BPB  ((int)(NVOX / VPB))   // 1024 blocks per batch
#define NBLK (NB * BPB)            // 2048 blocks
#define NCOPY 64                   // dice accumulator spreading
#define NHC  16                    // histogram spread copies (128 contenders/address)
#define NBINS 2048                 // 11-bit bins: sign(0)+exp(8)+mantissa(3)
#define SH   20                    // bin = bits >> 20 (CE >= 0 so sign bit = 0)
#define FIXS 262144.0f             // 2^18 fixed-point scale for packed bin sums

__device__ __forceinline__ float wred64(float v) {
#pragma unroll
  for (int o = 32; o > 0; o >>= 1) v += __shfl_down(v, o, 64);
  return v;
}

// Zero the accumulators (replaces hipMemsetAsync — one overhead suspect).
__global__ __launch_bounds__(256) void k_zero(float4* __restrict__ p, int n4) {
  int i = blockIdx.x * 256 + threadIdx.x;
  if (i < n4) p[i] = make_float4(0.f, 0.f, 0.f, 0.f);
}

// Single data pass: CE per voxel -> packed {count,sum} LDS histogram
// (one 64-bit LDS atomic per voxel); dice partial sums.
__global__ __launch_bounds__(TPB, 8) void k1_fused(
    const float* __restrict__ logits, const float* __restrict__ target,
    uint32_t* __restrict__ hcnt, float* __restrict__ hsum,
    float* __restrict__ dice_acc /* [NCOPY][NB][12]: sp[4], num[4], cnt[4] */)
{
  __shared__ unsigned long long hbin[NBINS];   // 16 KB -> 8 blocks/CU
  const int tid = threadIdx.x;
  for (int i = tid; i < NBINS; i += TPB) hbin[i] = 0ull;
  __syncthreads();

  const int blk = blockIdx.x;
  const int b = blk / BPB;
  const size_t v0 = (size_t)(blk % BPB) * VPB;
  const float* lg = logits + (size_t)b * 4 * NVOX + v0;
  const float* tg = target + (size_t)b * 4 * NVOX + v0;

  float sp[4] = {0.f,0.f,0.f,0.f}, nm[4] = {0.f,0.f,0.f,0.f}, ct[4] = {0.f,0.f,0.f,0.f};

  for (int i = tid * 4; i < VPB; i += TPB * 4) {
    float4 L[4], T[4];
#pragma unroll
    for (int c = 0; c < 4; ++c) {
      L[c] = *(const float4*)(lg + (size_t)c * NVOX + i);
      T[c] = *(const float4*)(tg + (size_t)c * NVOX + i);
    }
#pragma unroll
    for (int j = 0; j < 4; ++j) {
      float l[4], t[4];
#pragma unroll
      for (int c = 0; c < 4; ++c) {
        l[c] = ((const float*)&L[c])[j];
        t[c] = ((const float*)&T[c])[j];
      }
      float m = fmaxf(fmaxf(l[0], l[1]), fmaxf(l[2], l[3]));
      float e[4]; float s = 0.f;
#pragma unroll
      for (int c = 0; c < 4; ++c) { e[c] = __expf(l[c] - m); s += e[c]; }
      float inv = 1.f / s;
      float lse = __logf(s);                       // s >= 1 -> lse >= 0
      float ly = l[0]*t[0] + l[1]*t[1] + l[2]*t[2] + l[3]*t[3]; // exact: t one-hot
      float cev = (m - ly) + lse;                  // >= 0 (m >= ly, lse >= 0)
      uint32_t idx = __float_as_uint(cev) >> SH;   // monotone in cev; CE<16 -> <1048
      if (idx > NBINS - 1) idx = NBINS - 1;        // paranoia
      // count in bits[63:40]; sum as 2^18 fixed point in bits[39:0].
      // Per-block sum <= 2048 * 16 * 2^18 = 2^33 -> no carry into count.
      unsigned long long pk = (1ull << 40) | (unsigned long long)(cev * FIXS);
      atomicAdd(&hbin[idx], pk);
#pragma unroll
      for (int c = 0; c < 4; ++c) {
        float p = e[c] * inv;
        sp[c] += p;
        nm[c] += p * t[c];
        ct[c] += t[c];
      }
    }
  }

  // dice: wave-reduce then one atomic per component per wave into a spread copy
#pragma unroll
  for (int c = 0; c < 4; ++c) { sp[c] = wred64(sp[c]); nm[c] = wred64(nm[c]); ct[c] = wred64(ct[c]); }
  if ((tid & 63) == 0) {
    float* dst = dice_acc + ((size_t)(blk & (NCOPY - 1)) * NB + b) * 12;
#pragma unroll
    for (int c = 0; c < 4; ++c) {
      atomicAdd(dst + c,     sp[c]);
      atomicAdd(dst + 4 + c, nm[c]);
      atomicAdd(dst + 8 + c, ct[c]);
    }
  }
  __syncthreads();
  // Flush LDS histogram into this block's spread copy (~300 nonzero bins).
  const size_t hoff = ((size_t)b * NHC + (size_t)(blk & (NHC - 1))) * NBINS;
  uint32_t* cdst = hcnt + hoff;
  float*    sdst = hsum + hoff;
  for (int i = tid; i < NBINS; i += TPB) {
    unsigned long long v = hbin[i];
    if (v) {
      atomicAdd(&cdst[i], (uint32_t)(v >> 40));
      atomicAdd(&sdst[i], (float)(v & 0xFFFFFFFFFFull) * (1.0f / FIXS));
    }
  }
}

// Parallel collapse of the NHC spread copies -> one {count,sum} per bin.
// Grid: NB*2 blocks; each handles 1024 bins; fully coalesced uint4/float4.
__global__ __launch_bounds__(256) void k_reduce(
    const uint32_t* __restrict__ hcnt, const float* __restrict__ hsum,
    uint32_t* __restrict__ rcnt, float* __restrict__ rsum)
{
  const int b = blockIdx.x >> 1;
  const int seg = blockIdx.x & 1;
  const int base = seg * 1024 + threadIdx.x * 4;
  uint4 c = {0,0,0,0};
  float4 s = {0.f,0.f,0.f,0.f};
  for (int copy = 0; copy < NHC; ++copy) {
    const size_t off = ((size_t)b * NHC + copy) * NBINS + base;
    uint4 cv = *(const uint4*)(hcnt + off);
    float4 sv = *(const float4*)(hsum + off);
    c.x += cv.x; c.y += cv.y; c.z += cv.z; c.w += cv.w;
    s.x += sv.x; s.y += sv.y; s.z += sv.z; s.w += sv.w;
  }
  *(uint4*)(rcnt + (size_t)b * NBINS + base) = c;
  *(float4*)(rsum + (size_t)b * NBINS + base) = s;
}

// Final: per batch, top-down scan for the tie bin; topk_sum = exact sum of
// bins above + rem * (tie mean + uniform-density correction). Then dice.
__global__ __launch_bounds__(256) void k_final(
    const uint32_t* __restrict__ rcnt, const float* __restrict__ rsum,
    const float* __restrict__ dice_acc, float* __restrict__ out)
{
  __shared__ uint32_t shc[NBINS];   // 8 KB
  __shared__ uint32_t chunk[256];
  __shared__ uint32_t sbkt, srem;
  __shared__ float wpart[4];
  __shared__ float ts[NB];
  __shared__ float comp[24];
  const int tid = threadIdx.x;

  for (int b = 0; b < NB; ++b) {
    const uint32_t* rc = rcnt + (size_t)b * NBINS;
    const float*    rs = rsum + (size_t)b * NBINS;
    uint32_t s = 0;
#pragma unroll
    for (int q = 0; q < 2; ++q) {
      uint4 v = *(const uint4*)(rc + tid * 8 + q * 4);
      *(uint4*)&shc[tid * 8 + q * 4] = v;
      s += v.x + v.y + v.z + v.w;
    }
    chunk[tid] = s;
    __syncthreads();
    if (tid == 0) {
      uint32_t k = KSEL, cum = 0;
      int ci = 255;
      for (; ci > 0; --ci) {
        uint32_t c = chunk[ci];
        if (cum + c >= k) break;
        cum += c;
      }
      int bkt = ci * 8;
      for (int j = 7; j >= 0; --j) {
        uint32_t c = shc[ci * 8 + j];
        if (cum + c >= k) { bkt = ci * 8 + j; break; }
        cum += c;
      }
      sbkt = (uint32_t)bkt;
      srem = k - cum;              // 1 <= srem <= shc[bkt]
    }
    __syncthreads();
    const int bkt = (int)sbkt;
    // Exact sum of all bins strictly above the tie bin.
    float w = 0.f;
#pragma unroll
    for (int j = 0; j < 8; ++j) {
      int bin = tid * 8 + j;
      if (bin > bkt) w += rs[bin];
    }
    w = wred64(w);
    if ((tid & 63) == 0) wpart[tid >> 6] = w;
    __syncthreads();
    if (tid == 0) {
      float cnt_t = (float)shc[bkt];
      float sum_t = rs[bkt];
      float lo = __uint_as_float((uint32_t)bkt << SH);
      float hi = __uint_as_float((uint32_t)(bkt + 1) << SH);
      float width = hi - lo;
      float avg = sum_t / cnt_t;
      float frac = (float)srem / cnt_t;
      // uniform-density model: mean of the top-rem subset of the tie bin
      float est = avg + (1.f - frac) * 0.5f * width;
      ts[b] = wpart[0] + wpart[1] + wpart[2] + wpart[3] + (float)srem * est;
    }
    __syncthreads();   // shc/chunk reuse barrier for next batch
  }

  // dice: reduce the 64 spread copies of 24 components
  if (tid < 24) {
    float a = 0.f;
    for (int r = 0; r < NCOPY; ++r) a += dice_acc[(size_t)r * 24 + tid];
    comp[tid] = a;
  }
  __syncthreads();
  if (tid == 0) {
    float dl = 0.f;
#pragma unroll
    for (int b = 0; b < 2; ++b)
#pragma unroll
      for (int c = 1; c < 4; ++c) {
        float sp = comp[b * 12 + c];
        float nm = comp[b * 12 + 4 + c];
        float ct = comp[b * 12 + 8 + c];
        dl += 1.f - (2.f * nm) / (sp + ct + 1e-6f);
      }
    float topk = 0.5f * (ts[0] + ts[1]) / (float)KSEL;
    out[0] = topk + 0.5f * (dl / 6.f);
  }
}

extern "C" void kernel_launch(void* const* d_in, const int* in_sizes, int n_in,
                              void* d_out, int out_size, void* d_ws, size_t ws_size,
                              hipStream_t stream) {
  (void)in_sizes; (void)n_in; (void)out_size; (void)ws_size;
  const float* logits = (const float*)d_in[0];
  const float* target = (const float*)d_in[1];
  float* out = (float*)d_out;

  // Workspace layout:
  //   [hcnt 256KB][hsum 256KB][dice 6KB]  <- zeroed by k_zero
  //   [rcnt 8KB][rsum 8KB]                <- fully overwritten by k_reduce
  char* ws = (char*)d_ws;
  uint32_t* hcnt = (uint32_t*)ws;                          // NB*NHC*NBINS
  float*    hsum = (float*)(hcnt + (size_t)NB * NHC * NBINS);
  float*    dice_acc = hsum + (size_t)NB * NHC * NBINS;    // NCOPY*NB*12
  uint32_t* rcnt = (uint32_t*)(dice_acc + (size_t)NCOPY * NB * 12);
  float*    rsum = (float*)(rcnt + (size_t)NB * NBINS);
  const size_t ZERO_BYTES = (size_t)((char*)(dice_acc + (size_t)NCOPY * NB * 12) - ws);
  const int n4 = (int)(ZERO_BYTES / 16);   // layout sizes are 16B-multiples

  k_zero<<<(n4 + 255) / 256, 256, 0, stream>>>((float4*)ws, n4);
  k1_fused<<<NBLK, TPB, 0, stream>>>(logits, target, hcnt, hsum, dice_acc);
  k_reduce<<<NB * 2, 256, 0, stream>>>(hcnt, hsum, rcnt, rsum);
  k_final<<<1, 256, 0, stream>>>(rcnt, rsum, dice_acc, out);
}

// Round 8
// 179.941 us; speedup vs baseline: 1.0284x; 1.0284x over previous
//
#include <hip/hip_runtime.h>
#include <stdint.h>

// Problem constants (fixed by the reference setup):
//   logits (2,4,128,128,128) fp32, target one-hot same shape.
#define NVOX (1u << 21)            // 128^3 voxels per batch (exactly 2^21)
#define NB   2                     // batches
#define KSEL 419430u               // int(0.2 * 2^21)
#define TPB  256
#define VPB  4096                  // voxels per block (1024-block shape: best of R1-R7)
#define BPB  ((int)(NVOX / VPB))   // 512 blocks per batch
#define NBLK (NB * BPB)            // 1024 blocks
#define NBINS 2048                 // 11-bit bins: exp(8)+mantissa(3); covers full fp32 range
#define SH   20                    // bin = bits >> 20 (CE >= 0 so sign bit = 0)
#define FIXS 262144.0f             // 2^18 fixed-point scale for packed bin sums

typedef unsigned long long u64;

__device__ __forceinline__ float wred64(float v) {
#pragma unroll
  for (int o = 32; o > 0; o >>= 1) v += __shfl_down(v, o, 64);
  return v;
}

// Single data pass: CE per voxel -> packed {count,sum} LDS histogram (one
// 64-bit LDS atomic per voxel); per-block flush is PLAIN coalesced stores
// into a private slot — no global atomics, no pre-zeroed memory anywhere.
__global__ __launch_bounds__(TPB, 4) void k1_fused(
    const float* __restrict__ logits, const float* __restrict__ target,
    u64* __restrict__ hist /* [NBLK][NBINS] */,
    float* __restrict__ dice /* [NBLK][12]: sp[4], num[4], cnt[4] */)
{
  __shared__ u64 hbin[NBINS];      // 16 KB
  __shared__ float dsh[4][12];
  const int tid = threadIdx.x;
  for (int i = tid; i < NBINS; i += TPB) hbin[i] = 0ull;
  __syncthreads();

  const int blk = blockIdx.x;
  const int b = blk / BPB;
  const size_t v0 = (size_t)(blk % BPB) * VPB;
  const float* lg = logits + (size_t)b * 4 * NVOX + v0;
  const float* tg = target + (size_t)b * 4 * NVOX + v0;

  float sp[4] = {0.f,0.f,0.f,0.f}, nm[4] = {0.f,0.f,0.f,0.f}, ct[4] = {0.f,0.f,0.f,0.f};

#pragma unroll 2
  for (int i = tid * 4; i < VPB; i += TPB * 4) {
    float4 L[4], T[4];
#pragma unroll
    for (int c = 0; c < 4; ++c) {
      L[c] = *(const float4*)(lg + (size_t)c * NVOX + i);
      T[c] = *(const float4*)(tg + (size_t)c * NVOX + i);
    }
#pragma unroll
    for (int j = 0; j < 4; ++j) {
      float l[4], t[4];
#pragma unroll
      for (int c = 0; c < 4; ++c) {
        l[c] = ((const float*)&L[c])[j];
        t[c] = ((const float*)&T[c])[j];
      }
      float m = fmaxf(fmaxf(l[0], l[1]), fmaxf(l[2], l[3]));
      float e[4]; float s = 0.f;
#pragma unroll
      for (int c = 0; c < 4; ++c) { e[c] = __expf(l[c] - m); s += e[c]; }
      float inv = 1.f / s;
      float lse = __logf(s);                       // s >= 1 -> lse >= 0
      float ly = l[0]*t[0] + l[1]*t[1] + l[2]*t[2] + l[3]*t[3]; // exact: t one-hot
      float cev = (m - ly) + lse;                  // >= 0 (m >= ly, lse >= 0)
      uint32_t idx = __float_as_uint(cev) >> SH;   // monotone in cev; finite -> <=2039
      idx = min(idx, (uint32_t)(NBINS - 1));
      // count in bits[63:40]; sum as 2^18 fixed point in bits[39:0].
      // Per-block: count <= 4096 < 2^24; sum <= 4096*16*2^18 = 2^36 < 2^40.
      u64 pk = (1ull << 40) | (u64)(cev * FIXS);
      atomicAdd(&hbin[idx], pk);
#pragma unroll
      for (int c = 0; c < 4; ++c) {
        float p = e[c] * inv;
        sp[c] += p;
        nm[c] += p * t[c];
        ct[c] += t[c];
      }
    }
  }

  // dice: wave-reduce, combine the 4 waves in LDS, plain store 12 floats.
#pragma unroll
  for (int c = 0; c < 4; ++c) { sp[c] = wred64(sp[c]); nm[c] = wred64(nm[c]); ct[c] = wred64(ct[c]); }
  if ((tid & 63) == 0) {
    const int w = tid >> 6;
#pragma unroll
    for (int c = 0; c < 4; ++c) {
      dsh[w][c]     = sp[c];
      dsh[w][4 + c] = nm[c];
      dsh[w][8 + c] = ct[c];
    }
  }
  __syncthreads();                 // dsh ready AND all hbin atomics drained
  if (tid < 12)
    dice[(size_t)blk * 12 + tid] = dsh[0][tid] + dsh[1][tid] + dsh[2][tid] + dsh[3][tid];

  // Flush: plain coalesced u64 stores into this block's private slot.
  u64* hdst = hist + (size_t)blk * NBINS;
  for (int i = tid; i < NBINS; i += TPB) hdst[i] = hbin[i];
}

// Exact column-sum of the per-block histograms: for each (batch, bin), sum
// over the 512 blocks of that batch in u64 (no rounding). 64 blocks.
__global__ __launch_bounds__(256) void k_reduce(
    const u64* __restrict__ hist, uint32_t* __restrict__ rcnt,
    float* __restrict__ rsum)
{
  const int e = blockIdx.x;        // 64 blocks: batch = e>>5, 64-bin segment = e&31
  const int b = e >> 5;
  const int seg = e & 31;
  const int lane = threadIdx.x & 63;
  const int wave = threadIdx.x >> 6;
  const int bin = seg * 64 + lane;
  const u64* base = hist + (size_t)b * BPB * NBINS + bin;
  u64 csum = 0, fsum = 0;
  const int r0 = wave * (BPB / 4), r1 = r0 + BPB / 4;
  for (int r = r0; r < r1; ++r) {
    u64 v = base[(size_t)r * NBINS];   // 64 lanes -> 64 consecutive u64: coalesced
    csum += v >> 40;
    fsum += v & 0xFFFFFFFFFFull;
  }
  __shared__ u64 sc[4][64], ss[4][64];
  sc[wave][lane] = csum; ss[wave][lane] = fsum;
  __syncthreads();
  if (wave == 0) {
    csum = sc[0][lane] + sc[1][lane] + sc[2][lane] + sc[3][lane];
    fsum = ss[0][lane] + ss[1][lane] + ss[2][lane] + ss[3][lane];
    rcnt[b * NBINS + bin] = (uint32_t)csum;
    rsum[b * NBINS + bin] = (float)((double)fsum * (1.0 / 262144.0));
  }
}

// Final: per batch, top-down scan for the tie bin; topk_sum = exact sum of
// bins above + rem * (tie mean + uniform-density correction). Then dice.
__global__ __launch_bounds__(256) void k_final(
    const uint32_t* __restrict__ rcnt, const float* __restrict__ rsum,
    const float* __restrict__ dice, float* __restrict__ out)
{
  __shared__ uint32_t shc[NBINS];   // 8 KB
  __shared__ uint32_t chunk[256];
  __shared__ uint32_t sbkt, srem;
  __shared__ float wpart[4];
  __shared__ float ts[NB];
  __shared__ float cpart[4][24];
  const int tid = threadIdx.x;

  for (int b = 0; b < NB; ++b) {
    const uint32_t* rc = rcnt + (size_t)b * NBINS;
    const float*    rs = rsum + (size_t)b * NBINS;
    uint32_t s = 0;
#pragma unroll
    for (int q = 0; q < 2; ++q) {
      uint4 v = *(const uint4*)(rc + tid * 8 + q * 4);
      *(uint4*)&shc[tid * 8 + q * 4] = v;
      s += v.x + v.y + v.z + v.w;
    }
    chunk[tid] = s;
    __syncthreads();
    if (tid == 0) {
      uint32_t k = KSEL, cum = 0;
      int ci = 255;
      for (; ci > 0; --ci) {
        uint32_t c = chunk[ci];
        if (cum + c >= k) break;
        cum += c;
      }
      int bkt = ci * 8;
      for (int j = 7; j >= 0; --j) {
        uint32_t c = shc[ci * 8 + j];
        if (cum + c >= k) { bkt = ci * 8 + j; break; }
        cum += c;
      }
      sbkt = (uint32_t)bkt;
      srem = k - cum;              // 1 <= srem <= shc[bkt]
    }
    __syncthreads();
    const int bkt = (int)sbkt;
    // Exact sum of all bins strictly above the tie bin.
    float w = 0.f;
#pragma unroll
    for (int j = 0; j < 8; ++j) {
      int bin = tid * 8 + j;
      if (bin > bkt) w += rs[bin];
    }
    w = wred64(w);
    if ((tid & 63) == 0) wpart[tid >> 6] = w;
    __syncthreads();
    if (tid == 0) {
      float cnt_t = (float)shc[bkt];
      float sum_t = rs[bkt];
      float lo = __uint_as_float((uint32_t)bkt << SH);
      float hi = __uint_as_float((uint32_t)(bkt + 1) << SH);
      float width = hi - lo;
      float avg = sum_t / cnt_t;
      float frac = (float)srem / cnt_t;
      // uniform-density model: mean of the top-rem subset of the tie bin
      float est = avg + (1.f - frac) * 0.5f * width;
      ts[b] = wpart[0] + wpart[1] + wpart[2] + wpart[3] + (float)srem * est;
    }
    __syncthreads();   // shc/chunk reuse barrier for next batch
  }

  // dice: reduce the per-block partials [NBLK][12].
  float a0[12], a1[12];
#pragma unroll
  for (int c = 0; c < 12; ++c) { a0[c] = 0.f; a1[c] = 0.f; }
  for (int r = tid; r < NBLK; r += 256) {
    const float* dp = dice + (size_t)r * 12;
    if (r < BPB) {
#pragma unroll
      for (int c = 0; c < 12; ++c) a0[c] += dp[c];
    } else {
#pragma unroll
      for (int c = 0; c < 12; ++c) a1[c] += dp[c];
    }
  }
#pragma unroll
  for (int c = 0; c < 12; ++c) { a0[c] = wred64(a0[c]); a1[c] = wred64(a1[c]); }
  if ((tid & 63) == 0) {
    const int w = tid >> 6;
#pragma unroll
    for (int c = 0; c < 12; ++c) { cpart[w][c] = a0[c]; cpart[w][12 + c] = a1[c]; }
  }
  __syncthreads();
  if (tid == 0) {
    float comp[24];
#pragma unroll
    for (int c = 0; c < 24; ++c)
      comp[c] = cpart[0][c] + cpart[1][c] + cpart[2][c] + cpart[3][c];
    float dl = 0.f;
#pragma unroll
    for (int b = 0; b < 2; ++b)
#pragma unroll
      for (int c = 1; c < 4; ++c) {
        float sp = comp[b * 12 + c];
        float nm = comp[b * 12 + 4 + c];
        float ct = comp[b * 12 + 8 + c];
        dl += 1.f - (2.f * nm) / (sp + ct + 1e-6f);
      }
    float topk = 0.5f * (ts[0] + ts[1]) / (float)KSEL;
    out[0] = topk + 0.5f * (dl / 6.f);
  }
}

extern "C" void kernel_launch(void* const* d_in, const int* in_sizes, int n_in,
                              void* d_out, int out_size, void* d_ws, size_t ws_size,
                              hipStream_t stream) {
  (void)in_sizes; (void)n_in; (void)out_size; (void)ws_size;
  const float* logits = (const float*)d_in[0];
  const float* target = (const float*)d_in[1];
  float* out = (float*)d_out;

  // Workspace layout — every byte below is fully overwritten each call, so
  // no zeroing/memset is needed (poison-safe):
  //   [hist 16MB][dice 48KB][rcnt 16KB][rsum 16KB]
  char* ws = (char*)d_ws;
  u64*      hist = (u64*)ws;                               // NBLK*NBINS
  float*    dice = (float*)(hist + (size_t)NBLK * NBINS);  // NBLK*12
  uint32_t* rcnt = (uint32_t*)(dice + (size_t)NBLK * 12);  // NB*NBINS
  float*    rsum = (float*)(rcnt + (size_t)NB * NBINS);    // NB*NBINS

  k1_fused<<<NBLK, TPB, 0, stream>>>(logits, target, hist, dice);
  k_reduce<<<64, 256, 0, stream>>>(hist, rcnt, rsum);
  k_final<<<1, 256, 0, stream>>>(rcnt, rsum, dice, out);
}